// Round 1
// baseline (1408.620 us; speedup 1.0000x reference)
//
#include <hip/hip_runtime.h>

#define NN 8192
#define EE 2048
#define BB 512
#define TT 128
#define HH 128
#define G3 384
#define MAXNNZ 256

__device__ __forceinline__ float sigm(float x){ return 1.0f/(1.0f+__expf(-x)); }
__device__ __forceinline__ float tanhfast(float x){ return 2.0f/(1.0f+__expf(-2.0f*x)) - 1.0f; }

// ---- build per-edge nonzero index lists (Hbat is exactly binary) ----
__global__ __launch_bounds__(256)
void build_nnz(const float* __restrict__ Hb, int* __restrict__ idx, int* __restrict__ cnt){
  __shared__ int c;
  const int e = blockIdx.x;
  if (threadIdx.x == 0) c = 0;
  __syncthreads();
  const float* row = Hb + (size_t)e * NN;
  for (int n = threadIdx.x; n < NN; n += 256){
    if (row[n] != 0.0f){
      int p = atomicAdd(&c, 1);
      if (p < MAXNNZ) idx[e*MAXNNZ + p] = n;
    }
  }
  __syncthreads();
  if (threadIdx.x == 0) cnt[e] = (c < MAXNNZ ? c : MAXNNZ);
}

// ---- fp32 GEMM, K=128 fixed: C[row,col0+j] = sum_h A[row,h]*W(h, col0+j) + bias, optional row scale ----
template<int MT, bool TRANSW, bool SCALE>
__global__ __launch_bounds__(256)
void gemm128(const float* __restrict__ A, const float* __restrict__ W,
             const float* __restrict__ bias, const float* __restrict__ rowscale,
             float* __restrict__ C, int ldc)
{
  __shared__ float Wl[64*129];
  __shared__ float Al[64*(MT+4)];
  const int row0 = blockIdx.x * MT;
  const int col0 = blockIdx.y * 128;
  const int tid = threadIdx.x;
  const int j = tid & 127;
  const int q = tid >> 7;
  constexpr int RT = MT/2;
  float acc[RT];
  #pragma unroll
  for (int i=0;i<RT;i++) acc[i] = 0.0f;

  #pragma unroll 1
  for (int kk = 0; kk < 2; ++kk){
    if (kk) __syncthreads();
    if (TRANSW){
      #pragma unroll 1
      for (int p = tid; p < 128*64; p += 256){
        int g = p >> 6, hl = p & 63;
        Wl[hl*129 + g] = W[(size_t)(col0+g)*128 + kk*64 + hl];
      }
    } else {
      #pragma unroll 1
      for (int p = tid; p < 64*128; p += 256){
        int hl = p >> 7, cc = p & 127;
        Wl[hl*129 + cc] = W[(size_t)(kk*64+hl)*128 + col0 + cc];
      }
    }
    #pragma unroll 1
    for (int p = tid; p < MT*64; p += 256){
      int m = p >> 6, hl = p & 63;
      Al[hl*(MT+4) + m] = A[(size_t)(row0+m)*128 + kk*64 + hl];
    }
    __syncthreads();
    #pragma unroll 4
    for (int hl = 0; hl < 64; ++hl){
      float w = Wl[hl*129 + j];
      const float4* a4 = (const float4*)&Al[hl*(MT+4) + q*RT];
      #pragma unroll
      for (int i4 = 0; i4 < RT/4; ++i4){
        float4 av = a4[i4];
        acc[i4*4+0] += av.x * w;
        acc[i4*4+1] += av.y * w;
        acc[i4*4+2] += av.z * w;
        acc[i4*4+3] += av.w * w;
      }
    }
  }
  const float bv = bias[col0 + j];
  #pragma unroll
  for (int i = 0; i < RT; ++i){
    int m = row0 + q*RT + i;
    float cv = acc[i] + bv;
    if (SCALE) cv *= rowscale[m];
    C[(size_t)m*ldc + col0 + j] = cv;
  }
}

// ---- edge gather: Eb[e,:] = invDE[e] * sum_{n in edge e} Xs[n,:]  (Xs pre-scaled by DV2) ----
__global__ __launch_bounds__(128)
void edge_gather(const float* __restrict__ Xs, const int* __restrict__ idx,
                 const int* __restrict__ cnt, const float* __restrict__ invDE,
                 float* __restrict__ Eb){
  __shared__ int sidx[MAXNNZ];
  const int e = blockIdx.x, h = threadIdx.x;
  const int c = cnt[e];
  for (int k = h; k < c; k += 128) sidx[k] = idx[e*MAXNNZ + k];
  __syncthreads();
  float acc = 0.0f;
  int k = 0;
  for (; k + 4 <= c; k += 4){
    float a0 = Xs[(size_t)sidx[k+0]*HH + h];
    float a1 = Xs[(size_t)sidx[k+1]*HH + h];
    float a2 = Xs[(size_t)sidx[k+2]*HH + h];
    float a3 = Xs[(size_t)sidx[k+3]*HH + h];
    acc += (a0 + a1) + (a2 + a3);
  }
  for (; k < c; ++k) acc += Xs[(size_t)sidx[k]*HH + h];
  Eb[e*HH + h] = invDE[e] * acc;
}

// ---- node scatter: Xo[n,:] += Eb[e,:] for n in edge e ----
__global__ __launch_bounds__(128)
void node_scatter(const float* __restrict__ Eb, const int* __restrict__ idx,
                  const int* __restrict__ cnt, float* __restrict__ Xo){
  __shared__ int sidx[MAXNNZ];
  const int e = blockIdx.x, h = threadIdx.x;
  const int c = cnt[e];
  for (int k = h; k < c; k += 128) sidx[k] = idx[e*MAXNNZ + k];
  __syncthreads();
  const float v = Eb[e*HH + h];
  for (int k = 0; k < c; ++k)
    atomicAdd(&Xo[(size_t)sidx[k]*HH + h], v);
}

__global__ __launch_bounds__(256)
void finalize1(float* __restrict__ X, const float* __restrict__ DV2, const float* __restrict__ poi){
  int i = blockIdx.x*256 + threadIdx.x;
  float v = DV2[i >> 7] * X[i];
  X[i] = fmaxf(v, 0.0f) + poi[i];
}

__global__ __launch_bounds__(256)
void finalize2(float* __restrict__ X, const float* __restrict__ DV2){
  int i = blockIdx.x*256 + threadIdx.x;
  X[i] *= DV2[i >> 7];
}

__global__ __launch_bounds__(256)
void gather_emb(const float* __restrict__ X, const int* __restrict__ data, float* __restrict__ emb){
  int r = blockIdx.x*2 + (threadIdx.x >> 7);
  int h = threadIdx.x & 127;
  int n = data[r];
  emb[(size_t)r*HH + h] = X[(size_t)n*HH + h];
}

// ---- GRU scan: one block = 2 batch rows; thread g owns Whh[g,:] in 128 VGPRs ----
template<bool FINAL>
__global__ __launch_bounds__(384, 1)
void gru_scan(const float* __restrict__ gx, const float* __restrict__ Whh,
              const float* __restrict__ bhh, const float* __restrict__ emb,
              const int* __restrict__ lens, float* __restrict__ inp_out,
              float* __restrict__ final_out)
{
  const int g = threadIdx.x;
  const int b0 = blockIdx.x * 2;
  __shared__ __align__(16) float sh_h[2][128];
  __shared__ float sh_u[2][2][128];
  __shared__ float sh_xn[2][128];
  __shared__ float sh_hn[2][128];
  float4 w4[32];
  {
    const float4* wr = (const float4*)(Whh + (size_t)g*128);
    #pragma unroll
    for (int i=0;i<32;i++) w4[i] = wr[i];
  }
  const float bh = bhh[g];
  const int len0 = lens[b0], len1 = lens[b0+1];
  if (g < 128){ sh_h[0][g] = 0.0f; sh_h[1][g] = 0.0f; }
  __syncthreads();
  const int part = g >> 7, gg = g & 127;
  #pragma unroll 1
  for (int t = 0; t < TT; ++t){
    float gx0 = gx[((size_t)(b0+0)*TT + t)*G3 + g];
    float gx1 = gx[((size_t)(b0+1)*TT + t)*G3 + g];
    float acc0 = bh, acc1 = bh;
    const float4* h40 = (const float4*)&sh_h[0][0];
    const float4* h41 = (const float4*)&sh_h[1][0];
    #pragma unroll
    for (int i=0;i<32;i++){
      float4 hv0 = h40[i];
      float4 hv1 = h41[i];
      acc0 += w4[i].x*hv0.x + w4[i].y*hv0.y + w4[i].z*hv0.z + w4[i].w*hv0.w;
      acc1 += w4[i].x*hv1.x + w4[i].y*hv1.y + w4[i].z*hv1.z + w4[i].w*hv1.w;
    }
    if (part < 2){
      sh_u[0][part][gg] = gx0 + acc0;
      sh_u[1][part][gg] = gx1 + acc1;
    } else {
      sh_xn[0][gg] = gx0;  sh_hn[0][gg] = acc0;
      sh_xn[1][gg] = gx1;  sh_hn[1][gg] = acc1;
    }
    __syncthreads();
    if (g < 256){
      const int nb = part;
      const int hh = gg;
      float r = sigm(sh_u[nb][0][hh]);
      float z = sigm(sh_u[nb][1][hh]);
      float n = tanhfast(sh_xn[nb][hh] + r*sh_hn[nb][hh]);
      float hprev = sh_h[nb][hh];
      float hnew = (1.0f - z)*n + z*hprev;
      sh_h[nb][hh] = hnew;
      const int b = b0 + nb;
      const int len = nb ? len1 : len0;
      if (FINAL){
        if (t == len - 1) final_out[(size_t)b*HH + hh] = tanhfast(hnew);
      } else {
        float outv = (t < len) ? hnew : 0.0f;
        size_t ro = ((size_t)b*TT + t)*HH;
        inp_out[ro + hh] = emb[ro + hh] + fmaxf(outv, 0.0f);
      }
    }
    __syncthreads();
  }
}

extern "C" void kernel_launch(void* const* d_in, const int* in_sizes, int n_in,
                              void* d_out, int out_size, void* d_ws, size_t ws_size,
                              hipStream_t stream)
{
  const float* Hb    = (const float*)d_in[0];
  const float* DV2   = (const float*)d_in[1];
  const float* invDE = (const float*)d_in[2];
  const int*   data  = (const int*)d_in[3];
  const int*   dlen  = (const int*)d_in[4];
  const float* poi   = (const float*)d_in[5];
  const float* w1    = (const float*)d_in[6];
  const float* b1    = (const float*)d_in[7];
  const float* w2    = (const float*)d_in[8];
  const float* b2    = (const float*)d_in[9];
  const float* Wih   = (const float*)d_in[10];
  const float* Whh   = (const float*)d_in[11];
  const float* bih   = (const float*)d_in[12];
  const float* bhh   = (const float*)d_in[13];
  float* out = (float*)d_out;

  float* ws   = (float*)d_ws;
  float* x1s  = ws;                          // N*H (DV2-scaled conv1 pre-act)
  float* x2   = x1s + (size_t)NN*HH;         // N*H
  float* x3s  = x2  + (size_t)NN*HH;         // N*H
  float* x4   = x3s + (size_t)NN*HH;         // N*H
  float* ebuf = x4  + (size_t)NN*HH;         // E*H
  int*   idx  = (int*)(ebuf + (size_t)EE*HH);// E*MAXNNZ
  int*   cnt  = idx + (size_t)EE*MAXNNZ;     // E
  float* gx   = (float*)(cnt + EE);          // B*T*3H
  float* emb  = gx  + (size_t)BB*TT*G3;      // B*T*H
  float* inp  = emb + (size_t)BB*TT*HH;      // B*T*H

  // ---- hypergraph conv phase ----
  build_nnz<<<EE, 256, 0, stream>>>(Hb, idx, cnt);
  gemm128<32, false, true><<<dim3(NN/32, 1), 256, 0, stream>>>(poi, w1, b1, DV2, x1s, HH);
  edge_gather<<<EE, 128, 0, stream>>>(x1s, idx, cnt, invDE, ebuf);
  hipMemsetAsync(x2, 0, (size_t)NN*HH*sizeof(float), stream);
  node_scatter<<<EE, 128, 0, stream>>>(ebuf, idx, cnt, x2);
  finalize1<<<NN*HH/256, 256, 0, stream>>>(x2, DV2, poi);
  gemm128<32, false, true><<<dim3(NN/32, 1), 256, 0, stream>>>(x2, w2, b2, DV2, x3s, HH);
  edge_gather<<<EE, 128, 0, stream>>>(x3s, idx, cnt, invDE, ebuf);
  hipMemsetAsync(x4, 0, (size_t)NN*HH*sizeof(float), stream);
  node_scatter<<<EE, 128, 0, stream>>>(ebuf, idx, cnt, x4);
  finalize2<<<NN*HH/256, 256, 0, stream>>>(x4, DV2);
  gather_emb<<<BB*TT/2, 256, 0, stream>>>(x4, data, emb);

  // ---- GRU stack ----
  for (int l = 0; l < 3; ++l){
    const float* src = (l == 0) ? emb : inp;
    gemm128<64, true, false><<<dim3(BB*TT/64, 3), 256, 0, stream>>>(
        src, Wih + (size_t)l*G3*HH, bih + (size_t)l*G3, (const float*)nullptr, gx, G3);
    if (l < 2)
      gru_scan<false><<<BB/2, 384, 0, stream>>>(gx, Whh + (size_t)l*G3*HH,
          bhh + (size_t)l*G3, emb, dlen, inp, (float*)nullptr);
    else
      gru_scan<true><<<BB/2, 384, 0, stream>>>(gx, Whh + (size_t)l*G3*HH,
          bhh + (size_t)l*G3, emb, dlen, (float*)nullptr, out);
  }
}

// Round 4
// 1190.493 us; speedup vs baseline: 1.1832x; 1.1832x over previous
//
#include <hip/hip_runtime.h>

#define NN 8192
#define EE 2048
#define BB 512
#define TT 128
#define HH 128
#define G3 384
#define MAXNNZ 256

typedef __attribute__((ext_vector_type(8))) _Float16 f16x8;
typedef __attribute__((ext_vector_type(4))) float f32x4;

__device__ __forceinline__ float sigm(float x){ return 1.0f/(1.0f+__expf(-x)); }
__device__ __forceinline__ float tanhfast(float x){ return 2.0f/(1.0f+__expf(-2.0f*x)) - 1.0f; }

// ---- build per-edge nonzero index lists (Hbat is exactly binary) ----
__global__ __launch_bounds__(256)
void build_nnz(const float* __restrict__ Hb, int* __restrict__ idx, int* __restrict__ cnt){
  __shared__ int c;
  const int e = blockIdx.x;
  if (threadIdx.x == 0) c = 0;
  __syncthreads();
  const float* row = Hb + (size_t)e * NN;
  for (int n = threadIdx.x; n < NN; n += 256){
    if (row[n] != 0.0f){
      int p = atomicAdd(&c, 1);
      if (p < MAXNNZ) idx[e*MAXNNZ + p] = n;
    }
  }
  __syncthreads();
  if (threadIdx.x == 0) cnt[e] = (c < MAXNNZ ? c : MAXNNZ);
}

// ---- split (16*W) into fp16 hi/lo, row-major passthrough ----
__global__ __launch_bounds__(256)
void prep_w(const float* __restrict__ W, _Float16* __restrict__ whi,
            _Float16* __restrict__ wlo, int n){
  int i = blockIdx.x*256 + threadIdx.x;
  if (i >= n) return;
  float g = W[i] * 16.0f;
  _Float16 h = (_Float16)g;
  whi[i] = h;
  wlo[i] = (_Float16)(g - (float)h);
}

// ---- transpose + split (16*W) 128x128: wt[j,k] = 16*W[k,j] ----
__global__ __launch_bounds__(256)
void prep_wt(const float* __restrict__ W, _Float16* __restrict__ wt_hi,
             _Float16* __restrict__ wt_lo){
  int i = blockIdx.x*256 + threadIdx.x;   // 16384 total
  int k = i >> 7, j = i & 127;
  float g = W[i] * 16.0f;
  _Float16 h = (_Float16)g;
  wt_hi[j*HH + k] = h;
  wt_lo[j*HH + k] = (_Float16)(g - (float)h);
}

// ---- conv-phase MFMA GEMM: C[r,j] = rowscale[r] * (A@W + bias)  (W pre-transposed, x16)
template<bool SCALE>
__global__ __launch_bounds__(256)
void mm128_mfma(const float* __restrict__ A, const _Float16* __restrict__ Bh,
                const _Float16* __restrict__ Bl, const float* __restrict__ bias,
                const float* __restrict__ rowscale, float* __restrict__ C)
{
  const int tid = threadIdx.x;
  const int w = tid >> 6, l = tid & 63;
  const int lm = l & 15, q = l >> 4;
  const int r0 = blockIdx.x * 32;
  const int n0 = w * 32;

  f32x4 acc[2][2];
  #pragma unroll
  for (int m=0;m<2;m++)
    #pragma unroll
    for (int n=0;n<2;n++) acc[m][n] = (f32x4){0.f,0.f,0.f,0.f};

  #pragma unroll 1
  for (int ks = 0; ks < 4; ++ks){
    const int kb = ks*32 + q*8;
    f16x8 ah[2], al[2];
    #pragma unroll
    for (int m=0;m<2;m++){
      const float* pa = A + (size_t)(r0 + m*16 + lm)*HH + kb;
      float4 f0 = *(const float4*)pa;
      float4 f1 = *(const float4*)(pa+4);
      float fv[8] = {f0.x,f0.y,f0.z,f0.w,f1.x,f1.y,f1.z,f1.w};
      union { f16x8 v; _Float16 u[8]; } uh, ul;
      #pragma unroll
      for (int j=0;j<8;j++){
        _Float16 hh = (_Float16)fv[j];
        uh.u[j] = hh;
        ul.u[j] = (_Float16)(fv[j] - (float)hh);
      }
      ah[m] = uh.v; al[m] = ul.v;
    }
    #pragma unroll
    for (int n=0;n<2;n++){
      const int j = n0 + n*16 + lm;
      f16x8 bh = *(const f16x8*)(Bh + (size_t)j*HH + kb);
      f16x8 bl = *(const f16x8*)(Bl + (size_t)j*HH + kb);
      #pragma unroll
      for (int m=0;m<2;m++){
        acc[m][n] = __builtin_amdgcn_mfma_f32_16x16x32_f16(ah[m], bh, acc[m][n], 0,0,0);
        acc[m][n] = __builtin_amdgcn_mfma_f32_16x16x32_f16(al[m], bh, acc[m][n], 0,0,0);
        acc[m][n] = __builtin_amdgcn_mfma_f32_16x16x32_f16(ah[m], bl, acc[m][n], 0,0,0);
      }
    }
  }
  #pragma unroll
  for (int n=0;n<2;n++){
    const int j = n0 + n*16 + lm;
    const float bv = bias[j];
    #pragma unroll
    for (int m=0;m<2;m++){
      #pragma unroll
      for (int i=0;i<4;i++){
        int r = r0 + m*16 + q*4 + i;
        float cv = acc[m][n][i]*(1.0f/16.0f) + bv;
        if (SCALE) cv *= rowscale[r];
        C[(size_t)r*HH + j] = cv;
      }
    }
  }
}

// ---- edge gather: Eb[e,:] = invDE[e] * sum_{n in edge e} Xs[n,:] ----
__global__ __launch_bounds__(128)
void edge_gather(const float* __restrict__ Xs, const int* __restrict__ idx,
                 const int* __restrict__ cnt, const float* __restrict__ invDE,
                 float* __restrict__ Eb){
  __shared__ int sidx[MAXNNZ];
  const int e = blockIdx.x, h = threadIdx.x;
  const int c = cnt[e];
  for (int k = h; k < c; k += 128) sidx[k] = idx[e*MAXNNZ + k];
  __syncthreads();
  float acc = 0.0f;
  int k = 0;
  for (; k + 4 <= c; k += 4){
    float a0 = Xs[(size_t)sidx[k+0]*HH + h];
    float a1 = Xs[(size_t)sidx[k+1]*HH + h];
    float a2 = Xs[(size_t)sidx[k+2]*HH + h];
    float a3 = Xs[(size_t)sidx[k+3]*HH + h];
    acc += (a0 + a1) + (a2 + a3);
  }
  for (; k < c; ++k) acc += Xs[(size_t)sidx[k]*HH + h];
  Eb[e*HH + h] = invDE[e] * acc;
}

// ---- node scatter: Xo[n,:] += Eb[e,:] for n in edge e ----
__global__ __launch_bounds__(128)
void node_scatter(const float* __restrict__ Eb, const int* __restrict__ idx,
                  const int* __restrict__ cnt, float* __restrict__ Xo){
  __shared__ int sidx[MAXNNZ];
  const int e = blockIdx.x, h = threadIdx.x;
  const int c = cnt[e];
  for (int k = h; k < c; k += 128) sidx[k] = idx[e*MAXNNZ + k];
  __syncthreads();
  const float v = Eb[e*HH + h];
  for (int k = 0; k < c; ++k)
    atomicAdd(&Xo[(size_t)sidx[k]*HH + h], v);
}

__global__ __launch_bounds__(256)
void finalize1(float* __restrict__ X, const float* __restrict__ DV2, const float* __restrict__ poi){
  int i = blockIdx.x*256 + threadIdx.x;
  float v = DV2[i >> 7] * X[i];
  X[i] = fmaxf(v, 0.0f) + poi[i];
}

__global__ __launch_bounds__(256)
void finalize2(float* __restrict__ X, const float* __restrict__ DV2){
  int i = blockIdx.x*256 + threadIdx.x;
  X[i] *= DV2[i >> 7];
}

__global__ __launch_bounds__(256)
void gather_emb(const float* __restrict__ X, const int* __restrict__ data, float* __restrict__ emb){
  int r = blockIdx.x*2 + (threadIdx.x >> 7);
  int h = threadIdx.x & 127;
  int n = data[r];
  emb[(size_t)r*HH + h] = X[(size_t)n*HH + h];
}

// ---- gx = src @ Wih^T + bih, MFMA fp16 hi/lo (3-product ~ fp32 accuracy) ----
__global__ __launch_bounds__(256)
void gx_gemm(const float* __restrict__ A, const _Float16* __restrict__ Whi,
             const _Float16* __restrict__ Wlo, const float* __restrict__ bih,
             const int* __restrict__ lens, float* __restrict__ gx)
{
  const int blk = blockIdx.x;
  const int b = blk >> 2, tt = blk & 3;
  const int lenb = lens[b];
  if (tt*32 >= lenb) return;
  const int tid = threadIdx.x;
  const int w = tid >> 6, l = tid & 63;
  const int lm = l & 15, q = l >> 4;
  const int r0 = b*TT + tt*32;
  const int n0 = w*96;

  f32x4 acc[2][6];
  #pragma unroll
  for (int m=0;m<2;m++)
    #pragma unroll
    for (int n=0;n<6;n++) acc[m][n] = (f32x4){0.f,0.f,0.f,0.f};

  #pragma unroll 1
  for (int ks = 0; ks < 4; ++ks){
    const int kb = ks*32 + q*8;
    f16x8 ah[2], al[2];
    #pragma unroll
    for (int m=0;m<2;m++){
      const float* pa = A + (size_t)(r0 + m*16 + lm)*HH + kb;
      float4 f0 = *(const float4*)pa;
      float4 f1 = *(const float4*)(pa+4);
      float fv[8] = {f0.x,f0.y,f0.z,f0.w,f1.x,f1.y,f1.z,f1.w};
      union { f16x8 v; _Float16 u[8]; } uh, ul;
      #pragma unroll
      for (int j=0;j<8;j++){
        _Float16 hh = (_Float16)fv[j];
        uh.u[j] = hh;
        ul.u[j] = (_Float16)(fv[j] - (float)hh);
      }
      ah[m] = uh.v; al[m] = ul.v;
    }
    #pragma unroll
    for (int n=0;n<6;n++){
      const int g = n0 + n*16 + lm;
      f16x8 bh = *(const f16x8*)(Whi + (size_t)g*HH + kb);
      f16x8 bl = *(const f16x8*)(Wlo + (size_t)g*HH + kb);
      #pragma unroll
      for (int m=0;m<2;m++){
        acc[m][n] = __builtin_amdgcn_mfma_f32_16x16x32_f16(ah[m], bh, acc[m][n], 0,0,0);
        acc[m][n] = __builtin_amdgcn_mfma_f32_16x16x32_f16(al[m], bh, acc[m][n], 0,0,0);
        acc[m][n] = __builtin_amdgcn_mfma_f32_16x16x32_f16(ah[m], bl, acc[m][n], 0,0,0);
      }
    }
  }
  #pragma unroll
  for (int n=0;n<6;n++){
    const int g = n0 + n*16 + lm;
    const float bv = bih[g];
    #pragma unroll
    for (int m=0;m<2;m++){
      #pragma unroll
      for (int i=0;i<4;i++){
        int t = tt*32 + m*16 + q*4 + i;
        if (t < lenb)
          gx[((size_t)b*TT + t)*G3 + g] = acc[m][n][i]*(1.0f/16.0f) + bv;
      }
    }
  }
}

// ---- MFMA GRU scan, fp16 hi/lo-split h AND Whh (3-product, ~fp32 recurrence).
// 16 batches/block, 8 waves; wave w owns h-dims 16w..16w+15.
template<bool FINAL>
__global__ __launch_bounds__(512, 1)
void gru_scan_mfma(const float* __restrict__ gx, const float* __restrict__ Whh,
                   const float* __restrict__ bhh, const float* __restrict__ emb,
                   const int* __restrict__ lens, float* __restrict__ inp_out,
                   float* __restrict__ final_out)
{
  __shared__ _Float16 hb_hi[2][16*HH];
  __shared__ _Float16 hb_lo[2][16*HH];
  const int tid = threadIdx.x;
  const int w = tid >> 6, l = tid & 63;
  const int lm = l & 15, q = l >> 4;
  const int b0 = blockIdx.x * 16;
  const int d = w*16 + lm;

  // preload Whh*16 fragments hi/lo (B operand): wf*[ty][ks]
  f16x8 wfh[3][4], wfl[3][4];
  #pragma unroll
  for (int ty=0; ty<3; ++ty){
    const float* wr = Whh + (size_t)(ty*HH + d)*HH;
    #pragma unroll
    for (int ks=0; ks<4; ++ks){
      const int kb = ks*32 + q*8;
      float4 f0 = *(const float4*)(wr + kb);
      float4 f1 = *(const float4*)(wr + kb + 4);
      float fv[8] = {f0.x,f0.y,f0.z,f0.w,f1.x,f1.y,f1.z,f1.w};
      union { f16x8 v; _Float16 u[8]; } uh, ul;
      #pragma unroll
      for (int j=0;j<8;j++){
        float g = fv[j] * 16.0f;
        _Float16 hh = (_Float16)g;
        uh.u[j] = hh;
        ul.u[j] = (_Float16)(g - (float)hh);
      }
      wfh[ty][ks] = uh.v; wfl[ty][ks] = ul.v;
    }
  }
  const float bR = bhh[d], bZ = bhh[HH + d], bN = bhh[2*HH + d];

  int lenb[4];
  size_t gxrow[4], erow[4];
  #pragma unroll
  for (int i=0;i<4;i++){
    int bb = b0 + q*4 + i;
    lenb[i] = lens[bb];
    gxrow[i] = (size_t)bb*TT*G3 + w*16 + lm;
    erow[i]  = (size_t)bb*TT*HH + d;
  }
  const int lenmax = lens[b0];   // sorted descending -> max within block

  {   // zero h buffers
    unsigned int* z0 = (unsigned int*)&hb_hi[0][0];
    unsigned int* z1 = (unsigned int*)&hb_lo[0][0];
    for (int i = tid; i < 16*HH/2; i += 512){ z0[i] = 0u; z1[i] = 0u; }
  }
  float hp[4] = {0.f,0.f,0.f,0.f};
  __syncthreads();

  // prefetch t = 0
  float xv[12], ev[4] = {0.f,0.f,0.f,0.f};
  #pragma unroll
  for (int ty=0; ty<3; ++ty)
    #pragma unroll
    for (int i=0;i<4;i++)
      xv[ty*4+i] = gx[gxrow[i] + ty*HH];
  if (!FINAL){
    #pragma unroll
    for (int i=0;i<4;i++) ev[i] = emb[erow[i]];
  }

  int cur = 0;
  #pragma unroll 1
  for (int t = 0; t < lenmax; ++t){
    // A-frag reads (h of step t), hi and lo
    f16x8 avh[4], avl[4];
    #pragma unroll
    for (int ks=0; ks<4; ++ks){
      int off = (lm*256 + ks*64 + q*16) ^ ((lm & 7) << 4);
      avh[ks] = *(const f16x8*)((const char*)&hb_hi[cur][0] + off);
      avl[ks] = *(const f16x8*)((const char*)&hb_lo[cur][0] + off);
    }
    // prefetch t+1
    float xn_[12] = {0}; float en_[4] = {0};
    if (t+1 < lenmax){
      #pragma unroll
      for (int ty=0; ty<3; ++ty)
        #pragma unroll
        for (int i=0;i<4;i++)
          xn_[ty*4+i] = gx[gxrow[i] + (size_t)(t+1)*G3 + ty*HH];
      if (!FINAL){
        #pragma unroll
        for (int i=0;i<4;i++) en_[i] = emb[erow[i] + (size_t)(t+1)*HH];
      }
    }
    // gh = h @ (16*Whh)^T, 3-product hi/lo, 2 accumulation chains per gate
    f32x4 aR0 = (f32x4){0.f,0.f,0.f,0.f}, aR1 = aR0;
    f32x4 aZ0 = aR0, aZ1 = aR0, aN0 = aR0, aN1 = aR0;
    #pragma unroll
    for (int ks=0; ks<2; ++ks){
      aR0 = __builtin_amdgcn_mfma_f32_16x16x32_f16(avh[ks], wfh[0][ks], aR0, 0,0,0);
      aZ0 = __builtin_amdgcn_mfma_f32_16x16x32_f16(avh[ks], wfh[1][ks], aZ0, 0,0,0);
      aN0 = __builtin_amdgcn_mfma_f32_16x16x32_f16(avh[ks], wfh[2][ks], aN0, 0,0,0);
      aR0 = __builtin_amdgcn_mfma_f32_16x16x32_f16(avl[ks], wfh[0][ks], aR0, 0,0,0);
      aZ0 = __builtin_amdgcn_mfma_f32_16x16x32_f16(avl[ks], wfh[1][ks], aZ0, 0,0,0);
      aN0 = __builtin_amdgcn_mfma_f32_16x16x32_f16(avl[ks], wfh[2][ks], aN0, 0,0,0);
      aR0 = __builtin_amdgcn_mfma_f32_16x16x32_f16(avh[ks], wfl[0][ks], aR0, 0,0,0);
      aZ0 = __builtin_amdgcn_mfma_f32_16x16x32_f16(avh[ks], wfl[1][ks], aZ0, 0,0,0);
      aN0 = __builtin_amdgcn_mfma_f32_16x16x32_f16(avh[ks], wfl[2][ks], aN0, 0,0,0);
    }
    #pragma unroll
    for (int ks=2; ks<4; ++ks){
      aR1 = __builtin_amdgcn_mfma_f32_16x16x32_f16(avh[ks], wfh[0][ks], aR1, 0,0,0);
      aZ1 = __builtin_amdgcn_mfma_f32_16x16x32_f16(avh[ks], wfh[1][ks], aZ1, 0,0,0);
      aN1 = __builtin_amdgcn_mfma_f32_16x16x32_f16(avh[ks], wfh[2][ks], aN1, 0,0,0);
      aR1 = __builtin_amdgcn_mfma_f32_16x16x32_f16(avl[ks], wfh[0][ks], aR1, 0,0,0);
      aZ1 = __builtin_amdgcn_mfma_f32_16x16x32_f16(avl[ks], wfh[1][ks], aZ1, 0,0,0);
      aN1 = __builtin_amdgcn_mfma_f32_16x16x32_f16(avl[ks], wfh[2][ks], aN1, 0,0,0);
      aR1 = __builtin_amdgcn_mfma_f32_16x16x32_f16(avh[ks], wfl[0][ks], aR1, 0,0,0);
      aZ1 = __builtin_amdgcn_mfma_f32_16x16x32_f16(avh[ks], wfl[1][ks], aZ1, 0,0,0);
      aN1 = __builtin_amdgcn_mfma_f32_16x16x32_f16(avh[ks], wfl[2][ks], aN1, 0,0,0);
    }

    const int nxt = cur ^ 1;
    #pragma unroll
    for (int i=0;i<4;i++){
      float r = sigm(xv[0+i] + (aR0[i]+aR1[i])*(1.0f/16.0f) + bR);
      float z = sigm(xv[4+i] + (aZ0[i]+aZ1[i])*(1.0f/16.0f) + bZ);
      float n = tanhfast(xv[8+i] + r*((aN0[i]+aN1[i])*(1.0f/16.0f) + bN));
      float hnew = (1.0f - z)*n + z*hp[i];
      hp[i] = hnew;
      int bl_ = q*4 + i;
      int off = (bl_*256 + d*2) ^ ((bl_ & 7) << 4);
      _Float16 hh_ = (_Float16)hnew;
      *(_Float16*)((char*)&hb_hi[nxt][0] + off) = hh_;
      *(_Float16*)((char*)&hb_lo[nxt][0] + off) = (_Float16)(hnew - (float)hh_);
      if (!FINAL){
        if (t < lenb[i])
          inp_out[erow[i] + (size_t)t*HH] = ev[i] + fmaxf(hnew, 0.0f);
      } else {
        if (t == lenb[i] - 1)
          final_out[(size_t)(b0 + bl_)*HH + d] = tanhfast(hnew);
      }
    }
    #pragma unroll
    for (int k2=0;k2<12;k2++) xv[k2] = xn_[k2];
    if (!FINAL){
      #pragma unroll
      for (int i=0;i<4;i++) ev[i] = en_[i];
    }
    cur = nxt;
    __syncthreads();
  }
}

extern "C" void kernel_launch(void* const* d_in, const int* in_sizes, int n_in,
                              void* d_out, int out_size, void* d_ws, size_t ws_size,
                              hipStream_t stream)
{
  const float* Hb    = (const float*)d_in[0];
  const float* DV2   = (const float*)d_in[1];
  const float* invDE = (const float*)d_in[2];
  const int*   data  = (const int*)d_in[3];
  const int*   dlen  = (const int*)d_in[4];
  const float* poi   = (const float*)d_in[5];
  const float* w1    = (const float*)d_in[6];
  const float* b1    = (const float*)d_in[7];
  const float* w2    = (const float*)d_in[8];
  const float* b2    = (const float*)d_in[9];
  const float* Wih   = (const float*)d_in[10];
  const float* Whh   = (const float*)d_in[11];
  const float* bih   = (const float*)d_in[12];
  const float* bhh   = (const float*)d_in[13];
  float* out = (float*)d_out;

  float* ws   = (float*)d_ws;
  float* x1s  = ws;                          // N*H
  float* x2   = x1s + (size_t)NN*HH;         // N*H
  float* x3s  = x2  + (size_t)NN*HH;         // N*H
  float* x4   = x3s + (size_t)NN*HH;         // N*H
  float* ebuf = x4  + (size_t)NN*HH;         // E*H
  int*   idx  = (int*)(ebuf + (size_t)EE*HH);// E*MAXNNZ
  int*   cnt  = idx + (size_t)EE*MAXNNZ;     // E
  float* gx   = (float*)(cnt + EE);          // B*T*3H
  float* emb  = gx  + (size_t)BB*TT*G3;      // B*T*H
  float* inp  = emb + (size_t)BB*TT*HH;      // B*T*H
  _Float16* Whi = (_Float16*)(inp + (size_t)BB*TT*HH); // 3*384*128
  _Float16* Wlo = Whi + (size_t)3*G3*HH;
  _Float16* w1th = Wlo + (size_t)3*G3*HH;  // 128*128 each
  _Float16* w1tl = w1th + (size_t)HH*HH;
  _Float16* w2th = w1tl + (size_t)HH*HH;
  _Float16* w2tl = w2th + (size_t)HH*HH;

  // ---- prep ----
  build_nnz<<<EE, 256, 0, stream>>>(Hb, idx, cnt);
  prep_w<<<(3*G3*HH + 255)/256, 256, 0, stream>>>(Wih, Whi, Wlo, 3*G3*HH);
  prep_wt<<<HH*HH/256, 256, 0, stream>>>(w1, w1th, w1tl);
  prep_wt<<<HH*HH/256, 256, 0, stream>>>(w2, w2th, w2tl);

  // ---- hypergraph conv phase ----
  mm128_mfma<true><<<NN/32, 256, 0, stream>>>(poi, w1th, w1tl, b1, DV2, x1s);
  edge_gather<<<EE, 128, 0, stream>>>(x1s, idx, cnt, invDE, ebuf);
  hipMemsetAsync(x2, 0, (size_t)NN*HH*sizeof(float), stream);
  node_scatter<<<EE, 128, 0, stream>>>(ebuf, idx, cnt, x2);
  finalize1<<<NN*HH/256, 256, 0, stream>>>(x2, DV2, poi);
  mm128_mfma<true><<<NN/32, 256, 0, stream>>>(x2, w2th, w2tl, b2, DV2, x3s);
  edge_gather<<<EE, 128, 0, stream>>>(x3s, idx, cnt, invDE, ebuf);
  hipMemsetAsync(x4, 0, (size_t)NN*HH*sizeof(float), stream);
  node_scatter<<<EE, 128, 0, stream>>>(ebuf, idx, cnt, x4);
  finalize2<<<NN*HH/256, 256, 0, stream>>>(x4, DV2);
  gather_emb<<<BB*TT/2, 256, 0, stream>>>(x4, data, emb);

  // ---- GRU stack (MFMA) ----
  for (int l = 0; l < 3; ++l){
    const float* src = (l == 0) ? emb : inp;
    gx_gemm<<<BB*4, 256, 0, stream>>>(src, Whi + (size_t)l*G3*HH, Wlo + (size_t)l*G3*HH,
                                      bih + (size_t)l*G3, dlen, gx);
    if (l < 2)
      gru_scan_mfma<false><<<BB/16, 512, 0, stream>>>(gx, Whh + (size_t)l*G3*HH,
          bhh + (size_t)l*G3, emb, dlen, inp, (float*)nullptr);
    else
      gru_scan_mfma<true><<<BB/16, 512, 0, stream>>>(gx, Whh + (size_t)l*G3*HH,
          bhh + (size_t)l*G3, emb, dlen, (float*)nullptr, out);
  }
}

// Round 5
// 840.596 us; speedup vs baseline: 1.6757x; 1.4162x over previous
//
#include <hip/hip_runtime.h>

#define NN 8192
#define EE 2048
#define BB 512
#define TT 128
#define HH 128
#define G3 384
#define MAXNNZ 256
#define MAXDEG 96

typedef __attribute__((ext_vector_type(8))) _Float16 f16x8;
typedef __attribute__((ext_vector_type(4))) float f32x4;

__device__ __forceinline__ float sigm(float x){ return 1.0f/(1.0f+__expf(-x)); }
__device__ __forceinline__ float tanhfast(float x){ return 2.0f/(1.0f+__expf(-2.0f*x)) - 1.0f; }

// barrier that waits only LDS ops (keeps global prefetch loads in flight)
__device__ __forceinline__ void bar_lds(){
  asm volatile("s_waitcnt lgkmcnt(0)\n\ts_barrier" ::: "memory");
}

// ---- build per-edge nonzero index lists (Hbat is exactly binary) ----
__global__ __launch_bounds__(256)
void build_nnz(const float* __restrict__ Hb, int* __restrict__ idx, int* __restrict__ cnt){
  __shared__ int c;
  const int e = blockIdx.x;
  if (threadIdx.x == 0) c = 0;
  __syncthreads();
  const float* row = Hb + (size_t)e * NN;
  for (int n = threadIdx.x; n < NN; n += 256){
    if (row[n] != 0.0f){
      int p = atomicAdd(&c, 1);
      if (p < MAXNNZ) idx[e*MAXNNZ + p] = n;
    }
  }
  __syncthreads();
  if (threadIdx.x == 0) cnt[e] = (c < MAXNNZ ? c : MAXNNZ);
}

// ---- invert edge lists into per-node edge lists (removes scatter atomics) ----
__global__ __launch_bounds__(128)
void build_nodelists(const int* __restrict__ idx, const int* __restrict__ cnt,
                     int* __restrict__ ndeg, int* __restrict__ nidx){
  const int e = blockIdx.x;
  const int c = cnt[e];
  for (int k = threadIdx.x; k < c; k += 128){
    int n = idx[e*MAXNNZ + k];
    int p = atomicAdd(&ndeg[n], 1);
    if (p < MAXDEG) nidx[n*MAXDEG + p] = e;
  }
}

// ---- split (16*W) into fp16 hi/lo, row-major passthrough ----
__global__ __launch_bounds__(256)
void prep_w(const float* __restrict__ W, _Float16* __restrict__ whi,
            _Float16* __restrict__ wlo, int n){
  int i = blockIdx.x*256 + threadIdx.x;
  if (i >= n) return;
  float g = W[i] * 16.0f;
  _Float16 h = (_Float16)g;
  whi[i] = h;
  wlo[i] = (_Float16)(g - (float)h);
}

// ---- transpose + split (16*W) 128x128: wt[j,k] = 16*W[k,j] ----
__global__ __launch_bounds__(256)
void prep_wt(const float* __restrict__ W, _Float16* __restrict__ wt_hi,
             _Float16* __restrict__ wt_lo){
  int i = blockIdx.x*256 + threadIdx.x;   // 16384 total
  int k = i >> 7, j = i & 127;
  float g = W[i] * 16.0f;
  _Float16 h = (_Float16)g;
  wt_hi[j*HH + k] = h;
  wt_lo[j*HH + k] = (_Float16)(g - (float)h);
}

// ---- conv-phase MFMA GEMM: C[r,j] = rowscale[r] * (A@W + bias)  (W pre-transposed, x16)
template<bool SCALE>
__global__ __launch_bounds__(256)
void mm128_mfma(const float* __restrict__ A, const _Float16* __restrict__ Bh,
                const _Float16* __restrict__ Bl, const float* __restrict__ bias,
                const float* __restrict__ rowscale, float* __restrict__ C)
{
  const int tid = threadIdx.x;
  const int w = tid >> 6, l = tid & 63;
  const int lm = l & 15, q = l >> 4;
  const int r0 = blockIdx.x * 32;
  const int n0 = w * 32;

  f32x4 acc[2][2];
  #pragma unroll
  for (int m=0;m<2;m++)
    #pragma unroll
    for (int n=0;n<2;n++) acc[m][n] = (f32x4){0.f,0.f,0.f,0.f};

  #pragma unroll 1
  for (int ks = 0; ks < 4; ++ks){
    const int kb = ks*32 + q*8;
    f16x8 ah[2], al[2];
    #pragma unroll
    for (int m=0;m<2;m++){
      const float* pa = A + (size_t)(r0 + m*16 + lm)*HH + kb;
      float4 f0 = *(const float4*)pa;
      float4 f1 = *(const float4*)(pa+4);
      float fv[8] = {f0.x,f0.y,f0.z,f0.w,f1.x,f1.y,f1.z,f1.w};
      union { f16x8 v; _Float16 u[8]; } uh, ul;
      #pragma unroll
      for (int j=0;j<8;j++){
        _Float16 hh = (_Float16)fv[j];
        uh.u[j] = hh;
        ul.u[j] = (_Float16)(fv[j] - (float)hh);
      }
      ah[m] = uh.v; al[m] = ul.v;
    }
    #pragma unroll
    for (int n=0;n<2;n++){
      const int j = n0 + n*16 + lm;
      f16x8 bh = *(const f16x8*)(Bh + (size_t)j*HH + kb);
      f16x8 bl = *(const f16x8*)(Bl + (size_t)j*HH + kb);
      #pragma unroll
      for (int m=0;m<2;m++){
        acc[m][n] = __builtin_amdgcn_mfma_f32_16x16x32_f16(ah[m], bh, acc[m][n], 0,0,0);
        acc[m][n] = __builtin_amdgcn_mfma_f32_16x16x32_f16(al[m], bh, acc[m][n], 0,0,0);
        acc[m][n] = __builtin_amdgcn_mfma_f32_16x16x32_f16(ah[m], bl, acc[m][n], 0,0,0);
      }
    }
  }
  #pragma unroll
  for (int n=0;n<2;n++){
    const int j = n0 + n*16 + lm;
    const float bv = bias[j];
    #pragma unroll
    for (int m=0;m<2;m++){
      #pragma unroll
      for (int i=0;i<4;i++){
        int r = r0 + m*16 + q*4 + i;
        float cv = acc[m][n][i]*(1.0f/16.0f) + bv;
        if (SCALE) cv *= rowscale[r];
        C[(size_t)r*HH + j] = cv;
      }
    }
  }
}

// ---- edge gather: Eb[e,:] = invDE[e] * sum_{n in edge e} Xs[n,:] ----
__global__ __launch_bounds__(128)
void edge_gather(const float* __restrict__ Xs, const int* __restrict__ idx,
                 const int* __restrict__ cnt, const float* __restrict__ invDE,
                 float* __restrict__ Eb){
  __shared__ int sidx[MAXNNZ];
  const int e = blockIdx.x, h = threadIdx.x;
  const int c = cnt[e];
  for (int k = h; k < c; k += 128) sidx[k] = idx[e*MAXNNZ + k];
  __syncthreads();
  float acc = 0.0f;
  int k = 0;
  for (; k + 4 <= c; k += 4){
    float a0 = Xs[(size_t)sidx[k+0]*HH + h];
    float a1 = Xs[(size_t)sidx[k+1]*HH + h];
    float a2 = Xs[(size_t)sidx[k+2]*HH + h];
    float a3 = Xs[(size_t)sidx[k+3]*HH + h];
    acc += (a0 + a1) + (a2 + a3);
  }
  for (; k < c; ++k) acc += Xs[(size_t)sidx[k]*HH + h];
  Eb[e*HH + h] = invDE[e] * acc;
}

// ---- node gather: X[n,:] = epilogue( DV2[n] * sum_{e ∋ n} Eb[e,:] ) ----
template<int MODE>   // 1: relu(v)+poi   2: v
__global__ __launch_bounds__(128)
void node_gather(const float* __restrict__ Eb, const int* __restrict__ nidx,
                 const int* __restrict__ ndeg, const float* __restrict__ DV2,
                 const float* __restrict__ poi, float* __restrict__ Xo){
  __shared__ int sidx[MAXDEG];
  const int n = blockIdx.x, h = threadIdx.x;
  int c = ndeg[n]; c = c < MAXDEG ? c : MAXDEG;
  for (int k = h; k < c; k += 128) sidx[k] = nidx[n*MAXDEG + k];
  __syncthreads();
  float acc = 0.0f;
  int k = 0;
  for (; k + 4 <= c; k += 4){
    float a0 = Eb[(size_t)sidx[k+0]*HH + h];
    float a1 = Eb[(size_t)sidx[k+1]*HH + h];
    float a2 = Eb[(size_t)sidx[k+2]*HH + h];
    float a3 = Eb[(size_t)sidx[k+3]*HH + h];
    acc += (a0 + a1) + (a2 + a3);
  }
  for (; k < c; ++k) acc += Eb[(size_t)sidx[k]*HH + h];
  float v = DV2[n] * acc;
  if (MODE == 1) Xo[(size_t)n*HH + h] = fmaxf(v, 0.0f) + poi[(size_t)n*HH + h];
  else           Xo[(size_t)n*HH + h] = v;
}

__global__ __launch_bounds__(256)
void gather_emb(const float* __restrict__ X, const int* __restrict__ data, float* __restrict__ emb){
  int r = blockIdx.x*2 + (threadIdx.x >> 7);
  int h = threadIdx.x & 127;
  int n = data[r];
  emb[(size_t)r*HH + h] = X[(size_t)n*HH + h];
}

// ---- gx = (emb [+ relu(h)]) @ Wih^T + bih, MFMA fp16 hi/lo 3-product ----
template<bool FUSE>
__global__ __launch_bounds__(256)
void gx_gemm(const float* __restrict__ emb, const _Float16* __restrict__ hin,
             const _Float16* __restrict__ Whi, const _Float16* __restrict__ Wlo,
             const float* __restrict__ bih, const int* __restrict__ lens,
             float* __restrict__ gx)
{
  const int blk = blockIdx.x;
  const int b = blk >> 2, tt = blk & 3;
  const int lenb = lens[b];
  if (tt*32 >= lenb) return;
  const int tid = threadIdx.x;
  const int w = tid >> 6, l = tid & 63;
  const int lm = l & 15, q = l >> 4;
  const int r0 = b*TT + tt*32;
  const int n0 = w*96;

  f32x4 acc[2][6];
  #pragma unroll
  for (int m=0;m<2;m++)
    #pragma unroll
    for (int n=0;n<6;n++) acc[m][n] = (f32x4){0.f,0.f,0.f,0.f};

  #pragma unroll 1
  for (int ks = 0; ks < 4; ++ks){
    const int kb = ks*32 + q*8;
    f16x8 ah[2], al[2];
    #pragma unroll
    for (int m=0;m<2;m++){
      const size_t ro = (size_t)(r0 + m*16 + lm)*HH + kb;
      float4 f0 = *(const float4*)(emb + ro);
      float4 f1 = *(const float4*)(emb + ro + 4);
      float fv[8] = {f0.x,f0.y,f0.z,f0.w,f1.x,f1.y,f1.z,f1.w};
      if (FUSE){
        f16x8 hv = *(const f16x8*)(hin + ro);
        #pragma unroll
        for (int j=0;j<8;j++) fv[j] += fmaxf((float)hv[j], 0.0f);
      }
      union { f16x8 v; _Float16 u[8]; } uh, ul;
      #pragma unroll
      for (int j=0;j<8;j++){
        _Float16 hh = (_Float16)fv[j];
        uh.u[j] = hh;
        ul.u[j] = (_Float16)(fv[j] - (float)hh);
      }
      ah[m] = uh.v; al[m] = ul.v;
    }
    #pragma unroll
    for (int n=0;n<6;n++){
      const int g = n0 + n*16 + lm;
      f16x8 bh = *(const f16x8*)(Whi + (size_t)g*HH + kb);
      f16x8 bl = *(const f16x8*)(Wlo + (size_t)g*HH + kb);
      #pragma unroll
      for (int m=0;m<2;m++){
        acc[m][n] = __builtin_amdgcn_mfma_f32_16x16x32_f16(ah[m], bh, acc[m][n], 0,0,0);
        acc[m][n] = __builtin_amdgcn_mfma_f32_16x16x32_f16(al[m], bh, acc[m][n], 0,0,0);
        acc[m][n] = __builtin_amdgcn_mfma_f32_16x16x32_f16(ah[m], bl, acc[m][n], 0,0,0);
      }
    }
  }
  #pragma unroll
  for (int n=0;n<6;n++){
    const int g = n0 + n*16 + lm;
    const float bv = bih[g];
    #pragma unroll
    for (int m=0;m<2;m++){
      #pragma unroll
      for (int i=0;i<4;i++){
        int t = tt*32 + m*16 + q*4 + i;
        if (t < lenb)
          gx[((size_t)b*TT + t)*G3 + g] = acc[m][n][i]*(1.0f/16.0f) + bv;
      }
    }
  }
}

// ---- MFMA GRU scan, plain fp16 h and Whh (x16 scale). 16 batches/block, 8 waves.
// Raw lgkm-only barrier keeps the gx prefetch in flight across steps.
template<bool FINAL>
__global__ __launch_bounds__(512, 1)
void gru_scan_mfma(const float* __restrict__ gx, const float* __restrict__ Whh,
                   const float* __restrict__ bhh, const int* __restrict__ lens,
                   _Float16* __restrict__ hout, float* __restrict__ final_out)
{
  __shared__ _Float16 hbuf[2][16*HH];
  const int tid = threadIdx.x;
  const int w = tid >> 6, l = tid & 63;
  const int lm = l & 15, q = l >> 4;
  const int b0 = blockIdx.x * 16;
  const int d = w*16 + lm;

  // preload 16*Whh fragments (B operand): wf[ty][ks], plain fp16
  f16x8 wf[3][4];
  #pragma unroll
  for (int ty=0; ty<3; ++ty){
    const float* wr = Whh + (size_t)(ty*HH + d)*HH;
    #pragma unroll
    for (int ks=0; ks<4; ++ks){
      const int kb = ks*32 + q*8;
      float4 f0 = *(const float4*)(wr + kb);
      float4 f1 = *(const float4*)(wr + kb + 4);
      float fv[8] = {f0.x,f0.y,f0.z,f0.w,f1.x,f1.y,f1.z,f1.w};
      union { f16x8 v; _Float16 u[8]; } uu;
      #pragma unroll
      for (int j=0;j<8;j++) uu.u[j] = (_Float16)(fv[j] * 16.0f);
      wf[ty][ks] = uu.v;
    }
  }
  const float bR = bhh[d], bZ = bhh[HH + d], bN = bhh[2*HH + d];
  const float S = 1.0f/16.0f;

  int lenb[4];
  size_t gxrow[4], hrow[4];
  #pragma unroll
  for (int i=0;i<4;i++){
    int bb = b0 + q*4 + i;
    lenb[i] = lens[bb];
    gxrow[i] = (size_t)bb*TT*G3 + w*16 + lm;
    hrow[i]  = (size_t)bb*TT*HH + d;
  }
  const int lenmax = lens[b0];   // sorted descending -> max within block

  {   // zero h buffer 0
    unsigned int* z = (unsigned int*)&hbuf[0][0];
    for (int i = tid; i < 16*HH/2; i += 512) z[i] = 0u;
  }
  float hp[4] = {0.f,0.f,0.f,0.f};
  __syncthreads();

  // prefetch t = 0
  float xv[12];
  #pragma unroll
  for (int ty=0; ty<3; ++ty)
    #pragma unroll
    for (int i=0;i<4;i++)
      xv[ty*4+i] = gx[gxrow[i] + ty*HH];

  int cur = 0;
  #pragma unroll 1
  for (int t = 0; t < lenmax; ++t){
    // A-frag reads (h of step t) from hbuf[cur]
    f16x8 av[4];
    #pragma unroll
    for (int ks=0; ks<4; ++ks){
      int off = (lm*256 + ks*64 + q*16) ^ ((lm & 7) << 4);
      av[ks] = *(const f16x8*)((const char*)&hbuf[cur][0] + off);
    }
    // prefetch t+1 (stays in flight across the lgkm-only barrier)
    const int tp = (t+1 < lenmax) ? (t+1) : t;
    float xn_[12];
    #pragma unroll
    for (int ty=0; ty<3; ++ty)
      #pragma unroll
      for (int i=0;i<4;i++)
        xn_[ty*4+i] = gx[gxrow[i] + (size_t)tp*G3 + ty*HH];

    // gh = h @ (16*Whh)^T : 3 chains x 4 deep
    f32x4 aR = (f32x4){0.f,0.f,0.f,0.f};
    f32x4 aZ = aR, aN = aR;
    #pragma unroll
    for (int ks=0; ks<4; ++ks){
      aR = __builtin_amdgcn_mfma_f32_16x16x32_f16(av[ks], wf[0][ks], aR, 0,0,0);
      aZ = __builtin_amdgcn_mfma_f32_16x16x32_f16(av[ks], wf[1][ks], aZ, 0,0,0);
      aN = __builtin_amdgcn_mfma_f32_16x16x32_f16(av[ks], wf[2][ks], aN, 0,0,0);
    }

    const int nxt = cur ^ 1;
    #pragma unroll
    for (int i=0;i<4;i++){
      float r = sigm(xv[0+i] + aR[i]*S + bR);
      float z = sigm(xv[4+i] + aZ[i]*S + bZ);
      float n = tanhfast(xv[8+i] + r*(aN[i]*S + bN));
      float hnew = (1.0f - z)*n + z*hp[i];
      hp[i] = hnew;
      int bl_ = q*4 + i;
      int off = (bl_*256 + d*2) ^ ((bl_ & 7) << 4);
      *(_Float16*)((char*)&hbuf[nxt][0] + off) = (_Float16)hnew;
      if (!FINAL){
        if (t < lenb[i])
          hout[hrow[i] + (size_t)t*HH] = (_Float16)hnew;
      } else {
        if (t == lenb[i] - 1)
          final_out[(size_t)(b0 + bl_)*HH + d] = tanhfast(hnew);
      }
    }
    #pragma unroll
    for (int k2=0;k2<12;k2++) xv[k2] = xn_[k2];
    bar_lds();
    cur = nxt;
  }
}

extern "C" void kernel_launch(void* const* d_in, const int* in_sizes, int n_in,
                              void* d_out, int out_size, void* d_ws, size_t ws_size,
                              hipStream_t stream)
{
  const float* Hb    = (const float*)d_in[0];
  const float* DV2   = (const float*)d_in[1];
  const float* invDE = (const float*)d_in[2];
  const int*   data  = (const int*)d_in[3];
  const int*   dlen  = (const int*)d_in[4];
  const float* poi   = (const float*)d_in[5];
  const float* w1    = (const float*)d_in[6];
  const float* b1    = (const float*)d_in[7];
  const float* w2    = (const float*)d_in[8];
  const float* b2    = (const float*)d_in[9];
  const float* Wih   = (const float*)d_in[10];
  const float* Whh   = (const float*)d_in[11];
  const float* bih   = (const float*)d_in[12];
  const float* bhh   = (const float*)d_in[13];
  float* out = (float*)d_out;

  float* ws   = (float*)d_ws;
  float* x1s  = ws;                          // N*H
  float* x2   = x1s + (size_t)NN*HH;         // N*H
  float* x3s  = x2  + (size_t)NN*HH;         // N*H
  float* x4   = x3s + (size_t)NN*HH;         // N*H
  float* ebuf = x4  + (size_t)NN*HH;         // E*H
  int*   idx  = (int*)(ebuf + (size_t)EE*HH);// E*MAXNNZ
  int*   cnt  = idx + (size_t)EE*MAXNNZ;     // E
  float* gx   = (float*)(cnt + EE);          // B*T*3H
  float* emb  = gx  + (size_t)BB*TT*G3;      // B*T*H
  _Float16* hout = (_Float16*)(emb + (size_t)BB*TT*HH); // B*T*H fp16
  _Float16* Whi  = hout + (size_t)BB*TT*HH;  // 3*384*128
  _Float16* Wlo  = Whi + (size_t)3*G3*HH;
  _Float16* w1th = Wlo + (size_t)3*G3*HH;    // 128*128 each
  _Float16* w1tl = w1th + (size_t)HH*HH;
  _Float16* w2th = w1tl + (size_t)HH*HH;
  _Float16* w2tl = w2th + (size_t)HH*HH;
  int* ndeg = (int*)(w2tl + (size_t)HH*HH);  // N
  int* nidx = ndeg + NN;                     // N*MAXDEG

  // ---- prep ----
  hipMemsetAsync(ndeg, 0, NN*sizeof(int), stream);
  build_nnz<<<EE, 256, 0, stream>>>(Hb, idx, cnt);
  build_nodelists<<<EE, 128, 0, stream>>>(idx, cnt, ndeg, nidx);
  prep_w<<<(3*G3*HH + 255)/256, 256, 0, stream>>>(Wih, Whi, Wlo, 3*G3*HH);
  prep_wt<<<HH*HH/256, 256, 0, stream>>>(w1, w1th, w1tl);
  prep_wt<<<HH*HH/256, 256, 0, stream>>>(w2, w2th, w2tl);

  // ---- hypergraph conv phase ----
  mm128_mfma<true><<<NN/32, 256, 0, stream>>>(poi, w1th, w1tl, b1, DV2, x1s);
  edge_gather<<<EE, 128, 0, stream>>>(x1s, idx, cnt, invDE, ebuf);
  node_gather<1><<<NN, 128, 0, stream>>>(ebuf, nidx, ndeg, DV2, poi, x2);
  mm128_mfma<true><<<NN/32, 256, 0, stream>>>(x2, w2th, w2tl, b2, DV2, x3s);
  edge_gather<<<EE, 128, 0, stream>>>(x3s, idx, cnt, invDE, ebuf);
  node_gather<2><<<NN, 128, 0, stream>>>(ebuf, nidx, ndeg, DV2, (const float*)nullptr, x4);
  gather_emb<<<BB*TT/2, 256, 0, stream>>>(x4, data, emb);

  // ---- GRU stack (MFMA) ----
  for (int l = 0; l < 3; ++l){
    if (l == 0)
      gx_gemm<false><<<BB*4, 256, 0, stream>>>(emb, (const _Float16*)nullptr,
          Whi + (size_t)l*G3*HH, Wlo + (size_t)l*G3*HH, bih + (size_t)l*G3, dlen, gx);
    else
      gx_gemm<true><<<BB*4, 256, 0, stream>>>(emb, hout,
          Whi + (size_t)l*G3*HH, Wlo + (size_t)l*G3*HH, bih + (size_t)l*G3, dlen, gx);
    if (l < 2)
      gru_scan_mfma<false><<<BB/16, 512, 0, stream>>>(gx, Whh + (size_t)l*G3*HH,
          bhh + (size_t)l*G3, dlen, hout, (float*)nullptr);
    else
      gru_scan_mfma<true><<<BB/16, 512, 0, stream>>>(gx, Whh + (size_t)l*G3*HH,
          bhh + (size_t)l*G3, dlen, (_Float16*)nullptr, out);
  }
}